// Round 7
// baseline (514.323 us; speedup 1.0000x reference)
//
#include <hip/hip_runtime.h>

// ---------- helpers ----------
__device__ __forceinline__ unsigned short f2b(float f) {
    unsigned int u = __builtin_bit_cast(unsigned int, f);
    unsigned int r = (u + 0x7FFFu + ((u >> 16) & 1u)) >> 16;  // RNE
    return (unsigned short)r;
}
__device__ __forceinline__ float b2f(unsigned short s) {
    unsigned int u = ((unsigned int)s) << 16;
    return __builtin_bit_cast(float, u);
}

typedef __attribute__((ext_vector_type(8))) short short8;
typedef __attribute__((ext_vector_type(4))) float float4v;

#define GLD16(g, l) __builtin_amdgcn_global_load_lds(                          \
    (const __attribute__((address_space(1))) unsigned int*)(g),                \
    (__attribute__((address_space(3))) unsigned int*)(l), 16, 0, 0)

// s_waitcnt imm: vmcnt lo[3:0], expcnt[6:4], lgkmcnt[11:8]
#define WAIT_VMN(n)  __builtin_amdgcn_s_waitcnt(0x0F70 | (n))   // vmcnt(n), lgkm/exp free
#define SB()         __builtin_amdgcn_sched_barrier(0)
#define BAR()        __builtin_amdgcn_s_barrier()

// L=16384, D_IN=512, D_H=1024, D_OUT=512
#define SEQLEN 16384
#define NCHUNK 512
#define TCHUNK 32
#define LDH 2560   // Hcat row stride (cols: [0,2048)=Bu/h, [2048,2560)=x_bf16)

// ---------- merged prep: xcast + prep_B + prep_CW + zero(barrier counters) ----------
__global__ void prep_all(const float* __restrict__ x,
                         const float* __restrict__ B_re, const float* __restrict__ B_im,
                         const float* __restrict__ gamma,
                         const float* __restrict__ C_re, const float* __restrict__ C_im,
                         const float* __restrict__ Dm,
                         unsigned short* __restrict__ Hcat,
                         unsigned short* __restrict__ Bcat,
                         unsigned short* __restrict__ CW,
                         unsigned int* __restrict__ ctr) {
    int b = blockIdx.x;
    if (b < 8192) {
        int id = b * 256 + threadIdx.x;            // one per 4 elements of [16384 x 512]
        int t = id >> 7;
        int k4 = (id & 127) << 2;
        float4 v = *(const float4*)(x + (long)t * 512 + k4);
        ushort4 o;
        o.x = f2b(v.x); o.y = f2b(v.y); o.z = f2b(v.z); o.w = f2b(v.w);
        *(ushort4*)(Hcat + (long)t * LDH + 2048 + k4) = o;
    } else if (b < 9216) {
        int id = (b - 8192) * 256 + threadIdx.x;   // one per 4 elements of [2048 x 512]
        int n = id >> 7;
        int k4 = (id & 127) << 2;
        const float* src = (n < 1024) ? (B_re + (long)n * 512) : (B_im + (long)(n - 1024) * 512);
        float g = expf(gamma[n & 1023]);
        float4 v = *(const float4*)(src + k4);
        ushort4 o;
        o.x = f2b(v.x * g); o.y = f2b(v.y * g); o.z = f2b(v.z * g); o.w = f2b(v.w * g);
        *(ushort4*)(Bcat + (long)n * 512 + k4) = o;
    } else if (b < 10496) {
        int id = (b - 9216) * 256 + threadIdx.x;   // one per 4 elements of [512 x 2560]
        int o = id / 640;
        int j4 = (id - o * 640) << 2;
        float4 v; float sgn = 1.0f;
        if (j4 < 1024) {
            v = *(const float4*)(C_re + (long)o * 1024 + j4);
        } else if (j4 < 2048) {
            v = *(const float4*)(C_im + (long)o * 1024 + (j4 - 1024));
            sgn = -1.0f;
        } else {
            v = *(const float4*)(Dm + (long)o * 512 + (j4 - 2048));
        }
        ushort4 w;
        w.x = f2b(v.x * sgn); w.y = f2b(v.y * sgn); w.z = f2b(v.z * sgn); w.w = f2b(v.w * sgn);
        *(ushort4*)(CW + (long)o * 2560 + j4) = w;
    } else {
        // zero the scan_fused global-barrier counters (fresh each graph replay)
        if (threadIdx.x < 2) ctr[threadIdx.x] = 0u;
    }
}

// ---------- gemm_bu: 256x256 8-wave 4-phase (m201 geometry), bf16 out ----------
// Bu = x_bf16 @ Bcat^T. M=16384,N=2048,K=512 -> nk=8. grid 512 (8 XCD x 64).
__global__ __launch_bounds__(512, 1)
void gemm_bu(const unsigned short* __restrict__ A, int lda,
             const unsigned short* __restrict__ B, int ldb,
             unsigned short* __restrict__ Cout, int ldc) {
    constexpr int ASH = 16384;   // A shorts per buffer (256 x 64)
    __shared__ unsigned short sm[2][32768] __attribute__((aligned(16)));

    const int tid  = threadIdx.x;
    const int lane = tid & 63;
    const int wid  = tid >> 6;
    const int wr   = wid >> 2;          // wave row 0..1
    const int wc   = wid & 3;           // wave col 0..3

    const int bid = blockIdx.x;
    const int l = (bid & 7) * 64 + (bid >> 3);   // XCD-contiguous
    const long m0 = (long)(l >> 3) * 256;
    const long n0 = (long)(l & 7) * 256;

    const int sr = lane >> 3;
    const int sc = ((lane & 7) ^ sr) << 3;            // pre-swizzled global col-slot
    const unsigned short* Agl = A + (m0 + sr) * (long)lda + sc;
    const unsigned short* Bgl = B + (n0 + sr) * (long)ldb + sc;

    const int fr = lane & 15;
    const int x7 = fr & 7;
    const int k0off = (((lane >> 4)    ) ^ x7) << 3;
    const int k1off = (((lane >> 4) + 4) ^ x7) << 3;

    float4v acc[8][4] = {};
    short8 fa[4][2];
    short8 fb[4][2];

    auto stageB = [&](unsigned short* buf, long kt) {
        unsigned short* ldsB = buf + ASH + wid * 512;
        const unsigned short* gB = Bgl + kt;
#pragma unroll
        for (int i = 0; i < 4; i++)
            GLD16(gB + (long)(8 * (wid + 8 * i)) * ldb, ldsB + i * 4096);
    };
    auto stageA = [&](unsigned short* buf, long kt) {
        unsigned short* ldsA = buf + wid * 512;
        const unsigned short* gA = Agl + kt;
#pragma unroll
        for (int i = 0; i < 4; i++)
            GLD16(gA + (long)(8 * (wid + 8 * i)) * lda, ldsA + i * 4096);
    };
    auto ldA = [&](const unsigned short* buf, int mbase) {
#pragma unroll
        for (int i = 0; i < 4; i++) {
            const unsigned short* p = buf + (wr * 128 + (mbase + i) * 16 + fr) * 64;
            fa[i][0] = *(const short8*)(p + k0off);
            fa[i][1] = *(const short8*)(p + k1off);
        }
    };
    auto ldB = [&](const unsigned short* buf, int nbase) {
#pragma unroll
        for (int j = 0; j < 2; j++) {
            const unsigned short* p = buf + ASH + (wc * 64 + (nbase + j) * 16 + fr) * 64;
            fb[nbase + j][0] = *(const short8*)(p + k0off);
            fb[nbase + j][1] = *(const short8*)(p + k1off);
        }
    };
    auto mfmaQ = [&](int mbase, int nbase) {
        __builtin_amdgcn_s_setprio(1);
#pragma unroll
        for (int i = 0; i < 4; i++)
#pragma unroll
            for (int j = 0; j < 2; j++) {
                acc[mbase + i][nbase + j] = __builtin_amdgcn_mfma_f32_16x16x32_bf16(
                    fa[i][0], fb[nbase + j][0], acc[mbase + i][nbase + j], 0, 0, 0);
                acc[mbase + i][nbase + j] = __builtin_amdgcn_mfma_f32_16x16x32_bf16(
                    fa[i][1], fb[nbase + j][1], acc[mbase + i][nbase + j], 0, 0, 0);
            }
        __builtin_amdgcn_s_setprio(0);
    };

    const int nk = 8;
    stageB(sm[0], 0);  stageA(sm[0], 0);
    stageB(sm[1], 64); stageA(sm[1], 64);
    WAIT_VMN(8);
    SB(); BAR(); SB();

    for (int t = 0; t < nk; ++t) {
        unsigned short* cur = sm[t & 1];
        const bool st = (t + 2 < nk);
        const long kt2 = (long)(t + 2) * 64;
        ldA(cur, 0); ldB(cur, 0);
        SB(); BAR(); SB();
        mfmaQ(0, 0);
        SB(); BAR(); SB();
        ldB(cur, 2);
        SB(); BAR(); SB();
        mfmaQ(0, 2);
        SB(); BAR(); SB();
        if (st) stageB(cur, kt2);
        ldA(cur, 4);
        SB(); BAR(); SB();
        mfmaQ(4, 0);
        SB(); BAR(); SB();
        if (st) stageA(cur, kt2);
        SB();
        mfmaQ(4, 2);
        if (st)              WAIT_VMN(8);
        else if (t + 1 < nk) WAIT_VMN(0);
        SB(); BAR(); SB();
    }

    const int er = (lane >> 4) * 4;
    const int ec = lane & 15;
#pragma unroll
    for (int mi = 0; mi < 8; mi++) {
#pragma unroll
        for (int r = 0; r < 4; r++) {
            long grow = m0 + wr * 128 + mi * 16 + er + r;
#pragma unroll
            for (int nj = 0; nj < 4; nj++) {
                long gcol = n0 + wc * 64 + nj * 16 + ec;
                Cout[grow * ldc + gcol] = f2b(acc[mi][nj][r]);
            }
        }
    }
}

// ---------- gemm_y: 128x256 8-wave 4-phase (round-2 config, measured 53.2us) ----------
// y = Hcat @ CW^T -> d_out f32. M=16384,N=512,K=2560 -> nk=40. grid 256.
__global__ __launch_bounds__(512, 1)
void gemm_y(const unsigned short* __restrict__ A, int lda,
            const unsigned short* __restrict__ B, int ldb,
            float* __restrict__ Cout, int ldc) {
    constexpr int ASH = 8192;    // A shorts per buffer (128 x 64)
    __shared__ unsigned short sm[2][ASH + 16384] __attribute__((aligned(16)));

    const int tid  = threadIdx.x;
    const int lane = tid & 63;
    const int wid  = tid >> 6;
    const int wr   = wid >> 2;          // wave row 0..1
    const int wc   = wid & 3;           // wave col 0..3

    // bijective XCD swizzle, nbx_shift=1: bx = g&1, by = xcd*16 + (g>>1)
    const int bid = blockIdx.x;
    const int xcd = bid & 7;
    const int g   = bid >> 3;
    const int bx  = g & 1;
    const int by  = xcd * 16 + (g >> 1);
    const long m0 = (long)by * 128;
    const long n0 = (long)bx * 256;

    const int sr = lane >> 3;
    const int sc = ((lane & 7) ^ sr) << 3;
    const unsigned short* Agl = A + (m0 + sr) * (long)lda + sc;
    const unsigned short* Bgl = B + (n0 + sr) * (long)ldb + sc;

    const int fr = lane & 15;
    const int x7 = fr & 7;
    const int k0off = (((lane >> 4)    ) ^ x7) << 3;
    const int k1off = (((lane >> 4) + 4) ^ x7) << 3;

    float4v acc[4][4] = {};
    short8 fa[2][2];
    short8 fb[4][2];

    auto stageB = [&](unsigned short* buf, long kt) {
        unsigned short* ldsB = buf + ASH + wid * 512;
        const unsigned short* gB = Bgl + kt;
#pragma unroll
        for (int i = 0; i < 4; i++)
            GLD16(gB + (long)(8 * (wid + 8 * i)) * ldb, ldsB + i * 4096);
    };
    auto stageA = [&](unsigned short* buf, long kt) {
        unsigned short* ldsA = buf + wid * 512;
        const unsigned short* gA = Agl + kt;
#pragma unroll
        for (int i = 0; i < 2; i++)
            GLD16(gA + (long)(8 * (wid + 8 * i)) * lda, ldsA + i * 4096);
    };
    auto ldA = [&](const unsigned short* buf, int mbase) {
#pragma unroll
        for (int i = 0; i < 2; i++) {
            const unsigned short* p = buf + (wr * 64 + (mbase + i) * 16 + fr) * 64;
            fa[i][0] = *(const short8*)(p + k0off);
            fa[i][1] = *(const short8*)(p + k1off);
        }
    };
    auto ldB = [&](const unsigned short* buf, int nbase) {
#pragma unroll
        for (int j = 0; j < 2; j++) {
            const unsigned short* p = buf + ASH + (wc * 64 + (nbase + j) * 16 + fr) * 64;
            fb[nbase + j][0] = *(const short8*)(p + k0off);
            fb[nbase + j][1] = *(const short8*)(p + k1off);
        }
    };
    auto mfmaQ = [&](int mbase, int nbase) {
        __builtin_amdgcn_s_setprio(1);
#pragma unroll
        for (int i = 0; i < 2; i++)
#pragma unroll
            for (int j = 0; j < 2; j++) {
                acc[mbase + i][nbase + j] = __builtin_amdgcn_mfma_f32_16x16x32_bf16(
                    fa[i][0], fb[nbase + j][0], acc[mbase + i][nbase + j], 0, 0, 0);
                acc[mbase + i][nbase + j] = __builtin_amdgcn_mfma_f32_16x16x32_bf16(
                    fa[i][1], fb[nbase + j][1], acc[mbase + i][nbase + j], 0, 0, 0);
            }
        __builtin_amdgcn_s_setprio(0);
    };

    const int nk = 40;
    stageB(sm[0], 0);  stageA(sm[0], 0);
    stageB(sm[1], 64); stageA(sm[1], 64);
    WAIT_VMN(6);
    SB(); BAR(); SB();

    for (int t = 0; t < nk; ++t) {
        unsigned short* cur = sm[t & 1];
        const bool st = (t + 2 < nk);
        const long kt2 = (long)(t + 2) * 64;
        // P1: ds A(m lo) + B(n0-1); mfma
        ldA(cur, 0); ldB(cur, 0);
        SB(); BAR(); SB();
        mfmaQ(0, 0);
        SB(); BAR(); SB();
        // P2: ds B(n2-3); mfma   (B fully consumed after this)
        ldB(cur, 2);
        SB(); BAR(); SB();
        mfmaQ(0, 2);
        SB(); BAR(); SB();
        // P3: stage B(t+2) into cur (safe); ds A(m hi); mfma
        if (st) stageB(cur, kt2);
        ldA(cur, 2);
        SB(); BAR(); SB();
        mfmaQ(2, 0);
        SB(); BAR(); SB();
        // P4: stage A(t+2) into cur (safe); mfma; counted vmcnt
        if (st) stageA(cur, kt2);
        SB();
        mfmaQ(2, 2);
        if (st)              WAIT_VMN(6);
        else if (t + 1 < nk) WAIT_VMN(0);
        SB(); BAR(); SB();
    }

    const int er = (lane >> 4) * 4;
    const int ec = lane & 15;
#pragma unroll
    for (int mi = 0; mi < 4; mi++) {
#pragma unroll
        for (int r = 0; r < 4; r++) {
            long grow = m0 + wr * 64 + mi * 16 + er + r;
#pragma unroll
            for (int nj = 0; nj < 4; nj++) {
                long gcol = n0 + wc * 64 + nj * 16 + ec;
                Cout[grow * ldc + gcol] = acc[mi][nj][r];
            }
        }
    }
}

// ---------- fused scan: ends + carry + apply in ONE kernel ----------
// Grid 512 blocks x 256 threads, no LDS -> all blocks co-resident-capable
// (4 waves/block, 8 blocks/CU capacity >> 512 blocks), so the software
// global barrier cannot deadlock. Counters zeroed by prep_all each launch.
__device__ __forceinline__ void gbar(unsigned int* c, unsigned int tgt) {
    __threadfence();                       // publish my stores (device scope, G16)
    __syncthreads();
    if (threadIdx.x == 0) {
        atomicAdd(c, 1u);                  // device-scope by default
        while (__hip_atomic_load(c, __ATOMIC_ACQUIRE, __HIP_MEMORY_SCOPE_AGENT) < tgt)
            __builtin_amdgcn_s_sleep(2);
    }
    __syncthreads();
    __threadfence();                       // acquire side
}

__global__ __launch_bounds__(256)
void scan_fused(unsigned short* __restrict__ Hcat,
                const float* __restrict__ lamb,
                float* __restrict__ E, float* __restrict__ Kc,
                unsigned int* __restrict__ ctr) {
    const int chunk = blockIdx.x;          // 0..511
    const int ch4 = threadIdx.x << 2;      // 4 channels per thread
    float lre[4], lim[4];
#pragma unroll
    for (int i = 0; i < 4; i++) {
        float nu = expf(-expf(lamb[ch4 + i]));
        float th = expf(lamb[1024 + ch4 + i]);
        lre[i] = nu * cosf(th);
        lim[i] = nu * sinf(th);
    }

    // ---- phase 1: local chunk scan from h=0 -> E[chunk] ----
    unsigned short* base = Hcat + (long)chunk * TCHUNK * LDH + ch4;
    {
        float hr[4] = {0, 0, 0, 0}, hi[4] = {0, 0, 0, 0};
#pragma unroll 4
        for (int t = 0; t < TCHUNK; t++) {
            ushort4 br = *(const ushort4*)(base + (long)t * LDH);
            ushort4 bi = *(const ushort4*)(base + (long)t * LDH + 1024);
            float brf[4] = {b2f(br.x), b2f(br.y), b2f(br.z), b2f(br.w)};
            float bif[4] = {b2f(bi.x), b2f(bi.y), b2f(bi.z), b2f(bi.w)};
#pragma unroll
            for (int i = 0; i < 4; i++) {
                float nr = fmaf(lre[i], hr[i], fmaf(-lim[i], hi[i], brf[i]));
                float ni = fmaf(lre[i], hi[i], fmaf(lim[i], hr[i], bif[i]));
                hr[i] = nr; hi[i] = ni;
            }
        }
        float* Ec = E + (long)chunk * 2048 + ch4;
#pragma unroll
        for (int i = 0; i < 4; i++) {
            Ec[i] = hr[i];
            Ec[1024 + i] = hi[i];
        }
    }

    gbar(ctr + 0, NCHUNK);   // all E visible

    // ---- phase 2: wave-parallel Kogge-Stone carry (blocks 0..255) ----
    if (chunk < 256) {
        const int lane = threadIdx.x & 63;
        const int ch = chunk * 4 + (threadIdx.x >> 6);   // 0..1023
        double nu = exp(-exp((double)lamb[ch]));
        double th = exp((double)lamb[1024 + ch]);
        double lr = nu * cos(th), li = nu * sin(th);
#pragma unroll
        for (int i = 0; i < 5; i++) {      // T = lambda^32
            double rr = lr * lr - li * li;
            double ii = 2.0 * lr * li;
            lr = rr; li = ii;
        }
        const float tre = (float)lr, tim = (float)li;
        double ar = lr, ai = li;
#pragma unroll
        for (int i = 0; i < 3; i++) {      // T^8
            double rr = ar * ar - ai * ai;
            double ii = 2.0 * ar * ai;
            ar = rr; ai = ii;
        }
        float Ar = (float)ar, Ai = (float)ai;

        const int c0 = lane * 8;
        float er[8], ei[8];
#pragma unroll
        for (int j = 0; j < 8; j++) {
            er[j] = E[(long)(c0 + j) * 2048 + ch];
            ei[j] = E[(long)(c0 + j) * 2048 + 1024 + ch];
        }
        float hr = 0.0f, hi = 0.0f;
#pragma unroll
        for (int j = 0; j < 8; j++) {
            float nr = fmaf(tre, hr, fmaf(-tim, hi, er[j]));
            float ni = fmaf(tre, hi, fmaf(tim, hr, ei[j]));
            hr = nr; hi = ni;
        }
#pragma unroll
        for (int o = 1; o < 64; o <<= 1) {
            float pr = __shfl_up(hr, o);
            float pi = __shfl_up(hi, o);
            float qr = __shfl_up(Ar, o);
            float qi = __shfl_up(Ai, o);
            if (lane >= o) {
                float nr = fmaf(Ar, pr, fmaf(-Ai, pi, hr));
                float ni = fmaf(Ar, pi, fmaf(Ai, pr, hi));
                hr = nr; hi = ni;
                float nar = Ar * qr - Ai * qi;
                float nai = Ar * qi + Ai * qr;
                Ar = nar; Ai = nai;
            }
        }
        float sr = __shfl_up(hr, 1);
        float si = __shfl_up(hi, 1);
        if (lane == 0) { sr = 0.0f; si = 0.0f; }
#pragma unroll
        for (int j = 0; j < 8; j++) {
            Kc[(long)(c0 + j) * 2048 + ch] = sr;
            Kc[(long)(c0 + j) * 2048 + 1024 + ch] = si;
            float nr = fmaf(tre, sr, fmaf(-tim, si, er[j]));
            float ni = fmaf(tre, si, fmaf(tim, sr, ei[j]));
            sr = nr; si = ni;
        }
    }

    gbar(ctr + 1, NCHUNK);   // all Kc visible

    // ---- phase 3: replay chunk seeded with carry, in place (L3-resident re-read) ----
    {
        float hr[4], hi[4];
#pragma unroll
        for (int i = 0; i < 4; i++) {
            hr[i] = Kc[(long)chunk * 2048 + ch4 + i];
            hi[i] = Kc[(long)chunk * 2048 + 1024 + ch4 + i];
        }
#pragma unroll 4
        for (int t = 0; t < TCHUNK; t++) {
            ushort4 br = *(const ushort4*)(base + (long)t * LDH);
            ushort4 bi = *(const ushort4*)(base + (long)t * LDH + 1024);
            float brf[4] = {b2f(br.x), b2f(br.y), b2f(br.z), b2f(br.w)};
            float bif[4] = {b2f(bi.x), b2f(bi.y), b2f(bi.z), b2f(bi.w)};
#pragma unroll
            for (int i = 0; i < 4; i++) {
                float nr = fmaf(lre[i], hr[i], fmaf(-lim[i], hi[i], brf[i]));
                float ni = fmaf(lre[i], hi[i], fmaf(lim[i], hr[i], bif[i]));
                hr[i] = nr; hi[i] = ni;
            }
            ushort4 orv, oiv;
            orv.x = f2b(hr[0]); orv.y = f2b(hr[1]); orv.z = f2b(hr[2]); orv.w = f2b(hr[3]);
            oiv.x = f2b(hi[0]); oiv.y = f2b(hi[1]); oiv.z = f2b(hi[2]); oiv.w = f2b(hi[3]);
            *(ushort4*)(base + (long)t * LDH) = orv;
            *(ushort4*)(base + (long)t * LDH + 1024) = oiv;
        }
    }
}

// ---------- launch ----------
extern "C" void kernel_launch(void* const* d_in, const int* in_sizes, int n_in,
                              void* d_out, int out_size, void* d_ws, size_t ws_size,
                              hipStream_t stream) {
    const float* x     = (const float*)d_in[0];  // [16384, 512]
    const float* lamb  = (const float*)d_in[1];  // [2, 1024]
    const float* gamma = (const float*)d_in[2];  // [1024]
    const float* B_re  = (const float*)d_in[3];  // [1024, 512]
    const float* B_im  = (const float*)d_in[4];
    const float* C_re  = (const float*)d_in[5];  // [512, 1024]
    const float* C_im  = (const float*)d_in[6];
    const float* Dm    = (const float*)d_in[7];  // [512, 512]

    char* ws = (char*)d_ws;
    unsigned short* Hcat = (unsigned short*)ws;                      // 16384*2560*2 = 83886080
    float* E  = (float*)(ws + 83886080);                             // 512*2048*4 = 4194304
    float* Kc = E + (long)NCHUNK * 2048;                             // 4194304
    unsigned short* Bcat = (unsigned short*)((char*)Kc + 4194304);   // 2048*512*2 = 2097152
    unsigned short* CW   = Bcat + (long)2048 * 512;                  // 512*2560*2 = 2621440
    unsigned int* ctr    = (unsigned int*)((char*)CW + 2621440);     // 2 barrier counters

    prep_all<<<10497, 256, 0, stream>>>(x, B_re, B_im, gamma, C_re, C_im, Dm,
                                        Hcat, Bcat, CW, ctr);
    // Bu = x_bf16 @ Bcat^T -> Hcat cols [0,2048). 256^2 tiles: 64(by) x 8(bx) = 512 blocks.
    gemm_bu<<<512, 512, 0, stream>>>(Hcat + 2048, LDH, Bcat, 512, Hcat, LDH);
    // fused: local ends -> global barrier -> carry scan -> global barrier -> apply
    scan_fused<<<NCHUNK, 256, 0, stream>>>(Hcat, lamb, E, Kc, ctr);
    // y = Hcat @ CW^T -> d_out f32. 128(by) x 2(bx) = 256 blocks.
    gemm_y<<<256, 512, 0, stream>>>(Hcat, LDH, CW, 2560, (float*)d_out, 512);
}

// Round 8
// 234.247 us; speedup vs baseline: 2.1956x; 2.1956x over previous
//
#include <hip/hip_runtime.h>

// ---------- helpers ----------
__device__ __forceinline__ unsigned short f2b(float f) {
    unsigned int u = __builtin_bit_cast(unsigned int, f);
    unsigned int r = (u + 0x7FFFu + ((u >> 16) & 1u)) >> 16;  // RNE
    return (unsigned short)r;
}
__device__ __forceinline__ float b2f(unsigned short s) {
    unsigned int u = ((unsigned int)s) << 16;
    return __builtin_bit_cast(float, u);
}

typedef __attribute__((ext_vector_type(8))) short short8;
typedef __attribute__((ext_vector_type(4))) float float4v;

#define GLD16(g, l) __builtin_amdgcn_global_load_lds(                          \
    (const __attribute__((address_space(1))) unsigned int*)(g),                \
    (__attribute__((address_space(3))) unsigned int*)(l), 16, 0, 0)

// s_waitcnt imm: vmcnt lo[3:0], expcnt[6:4], lgkmcnt[11:8]
#define WAIT_VMN(n)  __builtin_amdgcn_s_waitcnt(0x0F70 | (n))   // vmcnt(n), lgkm/exp free
#define SB()         __builtin_amdgcn_sched_barrier(0)
#define BAR()        __builtin_amdgcn_s_barrier()

// L=16384, D_IN=512, D_H=1024, D_OUT=512
#define SEQLEN 16384
#define NCHUNK 512
#define TCHUNK 32
#define LDH 2560   // Hcat row stride (cols: [0,2048)=Bu/h, [2048,2560)=x_bf16)

// ---------- merged prep: xcast + prep_B + prep_CW ----------
__global__ void prep_all(const float* __restrict__ x,
                         const float* __restrict__ B_re, const float* __restrict__ B_im,
                         const float* __restrict__ gamma,
                         const float* __restrict__ C_re, const float* __restrict__ C_im,
                         const float* __restrict__ Dm,
                         unsigned short* __restrict__ Hcat,
                         unsigned short* __restrict__ Bcat,
                         unsigned short* __restrict__ CW) {
    int b = blockIdx.x;
    if (b < 8192) {
        int id = b * 256 + threadIdx.x;            // one per 4 elements of [16384 x 512]
        int t = id >> 7;
        int k4 = (id & 127) << 2;
        float4 v = *(const float4*)(x + (long)t * 512 + k4);
        ushort4 o;
        o.x = f2b(v.x); o.y = f2b(v.y); o.z = f2b(v.z); o.w = f2b(v.w);
        *(ushort4*)(Hcat + (long)t * LDH + 2048 + k4) = o;
    } else if (b < 9216) {
        int id = (b - 8192) * 256 + threadIdx.x;   // one per 4 elements of [2048 x 512]
        int n = id >> 7;
        int k4 = (id & 127) << 2;
        const float* src = (n < 1024) ? (B_re + (long)n * 512) : (B_im + (long)(n - 1024) * 512);
        float g = expf(gamma[n & 1023]);
        float4 v = *(const float4*)(src + k4);
        ushort4 o;
        o.x = f2b(v.x * g); o.y = f2b(v.y * g); o.z = f2b(v.z * g); o.w = f2b(v.w * g);
        *(ushort4*)(Bcat + (long)n * 512 + k4) = o;
    } else {
        int id = (b - 9216) * 256 + threadIdx.x;   // one per 4 elements of [512 x 2560]
        int o = id / 640;
        int j4 = (id - o * 640) << 2;
        float4 v; float sgn = 1.0f;
        if (j4 < 1024) {
            v = *(const float4*)(C_re + (long)o * 1024 + j4);
        } else if (j4 < 2048) {
            v = *(const float4*)(C_im + (long)o * 1024 + (j4 - 1024));
            sgn = -1.0f;
        } else {
            v = *(const float4*)(Dm + (long)o * 512 + (j4 - 2048));
        }
        ushort4 w;
        w.x = f2b(v.x * sgn); w.y = f2b(v.y * sgn); w.z = f2b(v.z * sgn); w.w = f2b(v.w * sgn);
        *(ushort4*)(CW + (long)o * 2560 + j4) = w;
    }
}

// ---------- gemm_bu: 256x256 8-wave 4-phase (m201 geometry), bf16 out ----------
// Bu = x_bf16 @ Bcat^T. M=16384,N=2048,K=512 -> nk=8. grid 512 (8 XCD x 64).
__global__ __launch_bounds__(512, 1)
void gemm_bu(const unsigned short* __restrict__ A, int lda,
             const unsigned short* __restrict__ B, int ldb,
             unsigned short* __restrict__ Cout, int ldc) {
    constexpr int ASH = 16384;   // A shorts per buffer (256 x 64)
    __shared__ unsigned short sm[2][32768] __attribute__((aligned(16)));

    const int tid  = threadIdx.x;
    const int lane = tid & 63;
    const int wid  = tid >> 6;
    const int wr   = wid >> 2;          // wave row 0..1
    const int wc   = wid & 3;           // wave col 0..3

    const int bid = blockIdx.x;
    const int l = (bid & 7) * 64 + (bid >> 3);   // XCD-contiguous
    const long m0 = (long)(l >> 3) * 256;
    const long n0 = (long)(l & 7) * 256;

    const int sr = lane >> 3;
    const int sc = ((lane & 7) ^ sr) << 3;            // pre-swizzled global col-slot
    const unsigned short* Agl = A + (m0 + sr) * (long)lda + sc;
    const unsigned short* Bgl = B + (n0 + sr) * (long)ldb + sc;

    const int fr = lane & 15;
    const int x7 = fr & 7;
    const int k0off = (((lane >> 4)    ) ^ x7) << 3;
    const int k1off = (((lane >> 4) + 4) ^ x7) << 3;

    float4v acc[8][4] = {};
    short8 fa[4][2];
    short8 fb[4][2];

    auto stageB = [&](unsigned short* buf, long kt) {
        unsigned short* ldsB = buf + ASH + wid * 512;
        const unsigned short* gB = Bgl + kt;
#pragma unroll
        for (int i = 0; i < 4; i++)
            GLD16(gB + (long)(8 * (wid + 8 * i)) * ldb, ldsB + i * 4096);
    };
    auto stageA = [&](unsigned short* buf, long kt) {
        unsigned short* ldsA = buf + wid * 512;
        const unsigned short* gA = Agl + kt;
#pragma unroll
        for (int i = 0; i < 4; i++)
            GLD16(gA + (long)(8 * (wid + 8 * i)) * lda, ldsA + i * 4096);
    };
    auto ldA = [&](const unsigned short* buf, int mbase) {
#pragma unroll
        for (int i = 0; i < 4; i++) {
            const unsigned short* p = buf + (wr * 128 + (mbase + i) * 16 + fr) * 64;
            fa[i][0] = *(const short8*)(p + k0off);
            fa[i][1] = *(const short8*)(p + k1off);
        }
    };
    auto ldB = [&](const unsigned short* buf, int nbase) {
#pragma unroll
        for (int j = 0; j < 2; j++) {
            const unsigned short* p = buf + ASH + (wc * 64 + (nbase + j) * 16 + fr) * 64;
            fb[nbase + j][0] = *(const short8*)(p + k0off);
            fb[nbase + j][1] = *(const short8*)(p + k1off);
        }
    };
    auto mfmaQ = [&](int mbase, int nbase) {
        __builtin_amdgcn_s_setprio(1);
#pragma unroll
        for (int i = 0; i < 4; i++)
#pragma unroll
            for (int j = 0; j < 2; j++) {
                acc[mbase + i][nbase + j] = __builtin_amdgcn_mfma_f32_16x16x32_bf16(
                    fa[i][0], fb[nbase + j][0], acc[mbase + i][nbase + j], 0, 0, 0);
                acc[mbase + i][nbase + j] = __builtin_amdgcn_mfma_f32_16x16x32_bf16(
                    fa[i][1], fb[nbase + j][1], acc[mbase + i][nbase + j], 0, 0, 0);
            }
        __builtin_amdgcn_s_setprio(0);
    };

    const int nk = 8;
    stageB(sm[0], 0);  stageA(sm[0], 0);
    stageB(sm[1], 64); stageA(sm[1], 64);
    WAIT_VMN(8);
    SB(); BAR(); SB();

    for (int t = 0; t < nk; ++t) {
        unsigned short* cur = sm[t & 1];
        const bool st = (t + 2 < nk);
        const long kt2 = (long)(t + 2) * 64;
        ldA(cur, 0); ldB(cur, 0);
        SB(); BAR(); SB();
        mfmaQ(0, 0);
        SB(); BAR(); SB();
        ldB(cur, 2);
        SB(); BAR(); SB();
        mfmaQ(0, 2);
        SB(); BAR(); SB();
        if (st) stageB(cur, kt2);
        ldA(cur, 4);
        SB(); BAR(); SB();
        mfmaQ(4, 0);
        SB(); BAR(); SB();
        if (st) stageA(cur, kt2);
        SB();
        mfmaQ(4, 2);
        if (st)              WAIT_VMN(8);
        else if (t + 1 < nk) WAIT_VMN(0);
        SB(); BAR(); SB();
    }

    const int er = (lane >> 4) * 4;
    const int ec = lane & 15;
#pragma unroll
    for (int mi = 0; mi < 8; mi++) {
#pragma unroll
        for (int r = 0; r < 4; r++) {
            long grow = m0 + wr * 128 + mi * 16 + er + r;
#pragma unroll
            for (int nj = 0; nj < 4; nj++) {
                long gcol = n0 + wc * 64 + nj * 16 + ec;
                Cout[grow * ldc + gcol] = f2b(acc[mi][nj][r]);
            }
        }
    }
}

// ---------- gemm_y: 128x256 8-wave 4-phase (round-2 config, measured 53.2us) ----------
// y = Hcat @ CW^T -> d_out f32. M=16384,N=512,K=2560 -> nk=40. grid 256.
__global__ __launch_bounds__(512, 1)
void gemm_y(const unsigned short* __restrict__ A, int lda,
            const unsigned short* __restrict__ B, int ldb,
            float* __restrict__ Cout, int ldc) {
    constexpr int ASH = 8192;    // A shorts per buffer (128 x 64)
    __shared__ unsigned short sm[2][ASH + 16384] __attribute__((aligned(16)));

    const int tid  = threadIdx.x;
    const int lane = tid & 63;
    const int wid  = tid >> 6;
    const int wr   = wid >> 2;          // wave row 0..1
    const int wc   = wid & 3;           // wave col 0..3

    // bijective XCD swizzle, nbx_shift=1: bx = g&1, by = xcd*16 + (g>>1)
    const int bid = blockIdx.x;
    const int xcd = bid & 7;
    const int g   = bid >> 3;
    const int bx  = g & 1;
    const int by  = xcd * 16 + (g >> 1);
    const long m0 = (long)by * 128;
    const long n0 = (long)bx * 256;

    const int sr = lane >> 3;
    const int sc = ((lane & 7) ^ sr) << 3;
    const unsigned short* Agl = A + (m0 + sr) * (long)lda + sc;
    const unsigned short* Bgl = B + (n0 + sr) * (long)ldb + sc;

    const int fr = lane & 15;
    const int x7 = fr & 7;
    const int k0off = (((lane >> 4)    ) ^ x7) << 3;
    const int k1off = (((lane >> 4) + 4) ^ x7) << 3;

    float4v acc[4][4] = {};
    short8 fa[2][2];
    short8 fb[4][2];

    auto stageB = [&](unsigned short* buf, long kt) {
        unsigned short* ldsB = buf + ASH + wid * 512;
        const unsigned short* gB = Bgl + kt;
#pragma unroll
        for (int i = 0; i < 4; i++)
            GLD16(gB + (long)(8 * (wid + 8 * i)) * ldb, ldsB + i * 4096);
    };
    auto stageA = [&](unsigned short* buf, long kt) {
        unsigned short* ldsA = buf + wid * 512;
        const unsigned short* gA = Agl + kt;
#pragma unroll
        for (int i = 0; i < 2; i++)
            GLD16(gA + (long)(8 * (wid + 8 * i)) * lda, ldsA + i * 4096);
    };
    auto ldA = [&](const unsigned short* buf, int mbase) {
#pragma unroll
        for (int i = 0; i < 2; i++) {
            const unsigned short* p = buf + (wr * 64 + (mbase + i) * 16 + fr) * 64;
            fa[i][0] = *(const short8*)(p + k0off);
            fa[i][1] = *(const short8*)(p + k1off);
        }
    };
    auto ldB = [&](const unsigned short* buf, int nbase) {
#pragma unroll
        for (int j = 0; j < 2; j++) {
            const unsigned short* p = buf + ASH + (wc * 64 + (nbase + j) * 16 + fr) * 64;
            fb[nbase + j][0] = *(const short8*)(p + k0off);
            fb[nbase + j][1] = *(const short8*)(p + k1off);
        }
    };
    auto mfmaQ = [&](int mbase, int nbase) {
        __builtin_amdgcn_s_setprio(1);
#pragma unroll
        for (int i = 0; i < 2; i++)
#pragma unroll
            for (int j = 0; j < 2; j++) {
                acc[mbase + i][nbase + j] = __builtin_amdgcn_mfma_f32_16x16x32_bf16(
                    fa[i][0], fb[nbase + j][0], acc[mbase + i][nbase + j], 0, 0, 0);
                acc[mbase + i][nbase + j] = __builtin_amdgcn_mfma_f32_16x16x32_bf16(
                    fa[i][1], fb[nbase + j][1], acc[mbase + i][nbase + j], 0, 0, 0);
            }
        __builtin_amdgcn_s_setprio(0);
    };

    const int nk = 40;
    stageB(sm[0], 0);  stageA(sm[0], 0);
    stageB(sm[1], 64); stageA(sm[1], 64);
    WAIT_VMN(6);
    SB(); BAR(); SB();

    for (int t = 0; t < nk; ++t) {
        unsigned short* cur = sm[t & 1];
        const bool st = (t + 2 < nk);
        const long kt2 = (long)(t + 2) * 64;
        // P1: ds A(m lo) + B(n0-1); mfma
        ldA(cur, 0); ldB(cur, 0);
        SB(); BAR(); SB();
        mfmaQ(0, 0);
        SB(); BAR(); SB();
        // P2: ds B(n2-3); mfma   (B fully consumed after this)
        ldB(cur, 2);
        SB(); BAR(); SB();
        mfmaQ(0, 2);
        SB(); BAR(); SB();
        // P3: stage B(t+2) into cur (safe); ds A(m hi); mfma
        if (st) stageB(cur, kt2);
        ldA(cur, 2);
        SB(); BAR(); SB();
        mfmaQ(2, 0);
        SB(); BAR(); SB();
        // P4: stage A(t+2) into cur (safe); mfma; counted vmcnt
        if (st) stageA(cur, kt2);
        SB();
        mfmaQ(2, 2);
        if (st)              WAIT_VMN(6);
        else if (t + 1 < nk) WAIT_VMN(0);
        SB(); BAR(); SB();
    }

    const int er = (lane >> 4) * 4;
    const int ec = lane & 15;
#pragma unroll
    for (int mi = 0; mi < 4; mi++) {
#pragma unroll
        for (int r = 0; r < 4; r++) {
            long grow = m0 + wr * 64 + mi * 16 + er + r;
#pragma unroll
            for (int nj = 0; nj < 4; nj++) {
                long gcol = n0 + wc * 64 + nj * 16 + ec;
                Cout[grow * ldc + gcol] = acc[mi][nj][r];
            }
        }
    }
}

// ---------- scan pass B: per-chunk local end states (zero-init) ----------
__global__ void scan_ends(const unsigned short* __restrict__ Hcat,
                          const float* __restrict__ lamb,
                          float* __restrict__ E) {
    const int chunk = blockIdx.x;
    const int ch = threadIdx.x << 2;   // 4 channels per thread
    float lre[4], lim[4];
#pragma unroll
    for (int i = 0; i < 4; i++) {
        float nu = expf(-expf(lamb[ch + i]));
        float th = expf(lamb[1024 + ch + i]);
        lre[i] = nu * cosf(th);
        lim[i] = nu * sinf(th);
    }
    float hr[4] = {0, 0, 0, 0}, hi[4] = {0, 0, 0, 0};
    const unsigned short* base = Hcat + (long)chunk * TCHUNK * LDH + ch;
#pragma unroll 4
    for (int t = 0; t < TCHUNK; t++) {
        ushort4 br = *(const ushort4*)(base + (long)t * LDH);
        ushort4 bi = *(const ushort4*)(base + (long)t * LDH + 1024);
        float brf[4] = {b2f(br.x), b2f(br.y), b2f(br.z), b2f(br.w)};
        float bif[4] = {b2f(bi.x), b2f(bi.y), b2f(bi.z), b2f(bi.w)};
#pragma unroll
        for (int i = 0; i < 4; i++) {
            float nr = fmaf(lre[i], hr[i], fmaf(-lim[i], hi[i], brf[i]));
            float ni = fmaf(lre[i], hi[i], fmaf(lim[i], hr[i], bif[i]));
            hr[i] = nr; hi[i] = ni;
        }
    }
    float* Ec = E + (long)chunk * 2048 + ch;
#pragma unroll
    for (int i = 0; i < 4; i++) {
        Ec[i] = hr[i];
        Ec[1024 + i] = hi[i];
    }
}

// ---------- scan pass C: wave-parallel chunk-carry scan ----------
// One wave per channel (4 waves/block, 256 blocks). Lane l owns chunks
// [8l, 8l+8): sequential local combine (A_seg = T^8 const), then 6-step
// Kogge-Stone inclusive scan over lanes, then exclusive-seeded replay.
__global__ void carry(const float* __restrict__ lamb, const float* __restrict__ E,
                      float* __restrict__ Kc) {
    const int lane = threadIdx.x & 63;
    const int ch = blockIdx.x * 4 + (threadIdx.x >> 6);  // 0..1023
    double nu = exp(-exp((double)lamb[ch]));
    double th = exp((double)lamb[1024 + ch]);
    double lr = nu * cos(th), li = nu * sin(th);
#pragma unroll
    for (int i = 0; i < 5; i++) {          // T = lambda^32
        double rr = lr * lr - li * li;
        double ii = 2.0 * lr * li;
        lr = rr; li = ii;
    }
    const float tre = (float)lr, tim = (float)li;
    double ar = lr, ai = li;
#pragma unroll
    for (int i = 0; i < 3; i++) {          // T^8
        double rr = ar * ar - ai * ai;
        double ii = 2.0 * ar * ai;
        ar = rr; ai = ii;
    }
    float Ar = (float)ar, Ai = (float)ai;

    const int c0 = lane * 8;
    float er[8], ei[8];
#pragma unroll
    for (int j = 0; j < 8; j++) {
        er[j] = E[(long)(c0 + j) * 2048 + ch];
        ei[j] = E[(long)(c0 + j) * 2048 + 1024 + ch];
    }
    float hr = 0.0f, hi = 0.0f;
#pragma unroll
    for (int j = 0; j < 8; j++) {
        float nr = fmaf(tre, hr, fmaf(-tim, hi, er[j]));
        float ni = fmaf(tre, hi, fmaf(tim, hr, ei[j]));
        hr = nr; hi = ni;
    }
#pragma unroll
    for (int o = 1; o < 64; o <<= 1) {
        float pr = __shfl_up(hr, o);
        float pi = __shfl_up(hi, o);
        float qr = __shfl_up(Ar, o);
        float qi = __shfl_up(Ai, o);
        if (lane >= o) {
            float nr = fmaf(Ar, pr, fmaf(-Ai, pi, hr));
            float ni = fmaf(Ar, pi, fmaf(Ai, pr, hi));
            hr = nr; hi = ni;
            float nar = Ar * qr - Ai * qi;
            float nai = Ar * qi + Ai * qr;
            Ar = nar; Ai = nai;
        }
    }
    float sr = __shfl_up(hr, 1);
    float si = __shfl_up(hi, 1);
    if (lane == 0) { sr = 0.0f; si = 0.0f; }
#pragma unroll
    for (int j = 0; j < 8; j++) {
        Kc[(long)(c0 + j) * 2048 + ch] = sr;
        Kc[(long)(c0 + j) * 2048 + 1024 + ch] = si;
        float nr = fmaf(tre, sr, fmaf(-tim, si, er[j]));
        float ni = fmaf(tre, si, fmaf(tim, sr, ei[j]));
        sr = nr; si = ni;
    }
}

// ---------- scan pass D: re-scan each chunk seeded with carry, IN PLACE ----------
__global__ void scan_apply(unsigned short* __restrict__ Hcat,
                           const float* __restrict__ lamb,
                           const float* __restrict__ Kc) {
    const int chunk = blockIdx.x;
    const int ch = threadIdx.x << 2;
    float lre[4], lim[4];
#pragma unroll
    for (int i = 0; i < 4; i++) {
        float nu = expf(-expf(lamb[ch + i]));
        float th = expf(lamb[1024 + ch + i]);
        lre[i] = nu * cosf(th);
        lim[i] = nu * sinf(th);
    }
    float hr[4], hi[4];
#pragma unroll
    for (int i = 0; i < 4; i++) {
        hr[i] = Kc[(long)chunk * 2048 + ch + i];
        hi[i] = Kc[(long)chunk * 2048 + 1024 + ch + i];
    }
    unsigned short* base = Hcat + (long)chunk * TCHUNK * LDH + ch;
#pragma unroll 4
    for (int t = 0; t < TCHUNK; t++) {
        ushort4 br = *(const ushort4*)(base + (long)t * LDH);
        ushort4 bi = *(const ushort4*)(base + (long)t * LDH + 1024);
        float brf[4] = {b2f(br.x), b2f(br.y), b2f(br.z), b2f(br.w)};
        float bif[4] = {b2f(bi.x), b2f(bi.y), b2f(bi.z), b2f(bi.w)};
#pragma unroll
        for (int i = 0; i < 4; i++) {
            float nr = fmaf(lre[i], hr[i], fmaf(-lim[i], hi[i], brf[i]));
            float ni = fmaf(lre[i], hi[i], fmaf(lim[i], hr[i], bif[i]));
            hr[i] = nr; hi[i] = ni;
        }
        ushort4 orv, oiv;
        orv.x = f2b(hr[0]); orv.y = f2b(hr[1]); orv.z = f2b(hr[2]); orv.w = f2b(hr[3]);
        oiv.x = f2b(hi[0]); oiv.y = f2b(hi[1]); oiv.z = f2b(hi[2]); oiv.w = f2b(hi[3]);
        *(ushort4*)(base + (long)t * LDH) = orv;
        *(ushort4*)(base + (long)t * LDH + 1024) = oiv;
    }
}

// ---------- launch ----------
extern "C" void kernel_launch(void* const* d_in, const int* in_sizes, int n_in,
                              void* d_out, int out_size, void* d_ws, size_t ws_size,
                              hipStream_t stream) {
    const float* x     = (const float*)d_in[0];  // [16384, 512]
    const float* lamb  = (const float*)d_in[1];  // [2, 1024]
    const float* gamma = (const float*)d_in[2];  // [1024]
    const float* B_re  = (const float*)d_in[3];  // [1024, 512]
    const float* B_im  = (const float*)d_in[4];
    const float* C_re  = (const float*)d_in[5];  // [512, 1024]
    const float* C_im  = (const float*)d_in[6];
    const float* Dm    = (const float*)d_in[7];  // [512, 512]

    char* ws = (char*)d_ws;
    unsigned short* Hcat = (unsigned short*)ws;                      // 16384*2560*2 = 83886080
    float* E  = (float*)(ws + 83886080);                             // 512*2048*4 = 4194304
    float* Kc = E + (long)NCHUNK * 2048;                             // 4194304
    unsigned short* Bcat = (unsigned short*)((char*)Kc + 4194304);   // 2048*512*2 = 2097152
    unsigned short* CW   = Bcat + (long)2048 * 512;                  // 512*2560*2 = 2621440

    prep_all<<<10496, 256, 0, stream>>>(x, B_re, B_im, gamma, C_re, C_im, Dm,
                                        Hcat, Bcat, CW);
    // Bu = x_bf16 @ Bcat^T -> Hcat cols [0,2048). 256^2 tiles: 64(by) x 8(bx) = 512 blocks.
    gemm_bu<<<512, 512, 0, stream>>>(Hcat + 2048, LDH, Bcat, 512, Hcat, LDH);
    scan_ends<<<NCHUNK, 256, 0, stream>>>(Hcat, lamb, E);
    carry<<<256, 256, 0, stream>>>(lamb, E, Kc);
    scan_apply<<<NCHUNK, 256, 0, stream>>>(Hcat, lamb, Kc);
    // y = Hcat @ CW^T -> d_out f32. 128(by) x 2(bx) = 256 blocks x 8 waves.
    gemm_y<<<256, 512, 0, stream>>>(Hcat, LDH, CW, 2560, (float*)d_out, 512);
}